// Round 9
// baseline (155.653 us; speedup 1.0000x reference)
//
#include <hip/hip_runtime.h>

#define I_DIM 28
#define H_DIM 64
#define T_DIM 128
#define B_DIM 4096
#define OUT_DIM 10
#define MB 16         // batch rows per block: full 16 MFMA B-columns
#define NTHREADS 512  // 8 symmetric waves; wave w owns h-rows w*8+2q+{0,1}
#define LOG2E 1.44269504088896340736f

typedef __attribute__((ext_vector_type(8))) short bf16x8;
typedef __attribute__((ext_vector_type(4))) float f32x4;
typedef __attribute__((ext_vector_type(4))) unsigned u32x4;

__device__ __forceinline__ float bfbits2f(unsigned b16) {
    return __builtin_bit_cast(float, b16 << 16);
}
// rne-rounded fp32 bits (bf16 lives in top 16 after the add)
__device__ __forceinline__ unsigned rne_u(float f) {
    unsigned u = __builtin_bit_cast(unsigned, f);
    return u + 0x7FFFu + ((u >> 16) & 1u);
}
// pack two floats -> (bf16(b)<<16)|bf16(a) : 2 rne-adds + 1 v_perm
__device__ __forceinline__ unsigned pack_pair(float a, float b) {
    return __builtin_amdgcn_perm(rne_u(b), rne_u(a), 0x07060302u);
}
__device__ __forceinline__ unsigned f2bf_rne(float f) { return rne_u(f) >> 16; }
__device__ __forceinline__ unsigned ftrunc_bf(float f) {
    return __builtin_bit_cast(unsigned, f) >> 16;
}

// 8 floats -> single rne-bf16 frag (4 dwords)
__device__ __forceinline__ bf16x8 pack_frag(const float* v) {
    u32x4 w;
    #pragma unroll
    for (int i = 0; i < 4; ++i) w[i] = pack_pair(v[2*i], v[2*i+1]);
    return __builtin_bit_cast(bf16x8, w);
}

// 8 floats -> hi/lo bf16 frags (used for W_ih only; startup)
__device__ __forceinline__ void split_frag(const float* v, bf16x8& hi, bf16x8& lo) {
    unsigned hb[8], lb[8];
    #pragma unroll
    for (int j = 0; j < 8; ++j) {
        hb[j] = f2bf_rne(v[j]);
        float rem = v[j] - bfbits2f(hb[j]);
        lb[j] = ftrunc_bf(rem);
    }
    u32x4 hw, lw;
    #pragma unroll
    for (int i = 0; i < 4; ++i) {
        hw[i] = (hb[2*i+1] << 16) | (hb[2*i] & 0xFFFFu);
        lw[i] = (lb[2*i+1] << 16) | (lb[2*i] & 0xFFFFu);
    }
    hi = __builtin_bit_cast(bf16x8, hw);
    lo = __builtin_bit_cast(bf16x8, lw);
}

__device__ __forceinline__ float fast_rcp(float v) { return __builtin_amdgcn_rcpf(v); }
__device__ __forceinline__ float exp2_f(float v)  { return __builtin_amdgcn_exp2f(v); }

// Merged single-rcp LSTM cell update, c carried as cs2 = 2*LOG2E*c.
// num2 = cs2*t1 + 2L(C-1)*oB ; cc2 = num2 * rcp(t1*oB)   (== 2L*c_new, exact 2x)
// E = 2^cc2 = e^(2c) ; h = (E-1) * rcp((1+D)(E+1))
// 5 exp + 2 rcp per cell; one chain op fewer than the cc form (no cc+cc).
__device__ __forceinline__ float cell_update(float ia, float fa, float ga,
                                             float oa, float& cs2) {
    float A  = exp2_f(-ia);
    float B  = exp2_f(-fa);
    float Cc = exp2_f(ga + ga);
    float D  = exp2_f(-oa);
    float oA = 1.0f + A;
    float oB = 1.0f + B;
    float Cp = Cc + 1.0f;
    float t1 = oA * Cp;                              // (1+A)(C+1)
    float t2 = fmaf(Cc, 2.0f * LOG2E, -2.0f * LOG2E);// 2L(C-1)
    float num = fmaf(cs2, t1, t2 * oB);
    float R1  = fast_rcp(t1 * oB);
    float cc2 = num * R1;                            // 2L*c
    cs2 = cc2;
    float E  = exp2_f(cc2);
    float R2 = fast_rcp((1.0f + D) * (E + 1.0f));
    return (E - 1.0f) * R2;                          // h = sig(o)*tanh(c)
}

#define MFMA(A, B, C) __builtin_amdgcn_mfma_f32_16x16x32_bf16((A), (B), (C), 0, 0, 0)

// Raw barrier with counted wait: LDS writes must be visible (lgkmcnt(0)),
// but global loads (x prefetch) stay in flight across the barrier.
#define BAR() do {                                              \
    asm volatile("s_waitcnt lgkmcnt(0)" ::: "memory");          \
    __builtin_amdgcn_s_barrier();                               \
} while (0)

__global__ __launch_bounds__(NTHREADS, 1)
void lstm_mfma_kernel(const float* __restrict__ x,
                      const float* __restrict__ W_ih,
                      const float* __restrict__ W_hh,
                      const float* __restrict__ b_ih,
                      const float* __restrict__ b_hh,
                      const float* __restrict__ W_out,
                      const float* __restrict__ b_out,
                      float* __restrict__ out)
{
    const int tid  = threadIdx.x;
    const int wv   = tid >> 6;        // wave 0..7
    const int lane = tid & 63;
    const int q    = lane >> 4;       // quad
    const int cm   = lane & 15;       // batch column (all 16 real)
    const int b0   = blockIdx.x * MB;

    // h state, single rne-bf16, B-frag dword order, double-buffered (4 KB)
    __shared__ __align__(16) unsigned hbuf[2][512];
    // x B-frags, [chunk parity][tt][frag dwords] (8 KB)
    __shared__ __align__(16) unsigned xbuf[2][2][256];

    // ---- resident A-frags (pre-scaled by LOG2E).
    // Row remap: tile m, A/C-row a: gate = a&3, h-row = wv*8 + 2*(a>>2) + m.
    // Lane (q,c) reg r of tile m = gate r's preact for cell (wv*8+2q+m, c):
    // all 4 gates in-lane; the lane's 2 cells are consecutive rows.
    bf16x8 Whh[2][2];        // [tile][K-chunk]
    bf16x8 Wih_hi[2], Wih_lo[2];
    f32x4  bias_c[2];
    #pragma unroll
    for (int m = 0; m < 2; ++m) {
        const int arow = (cm & 3) * H_DIM + wv * 8 + 2 * (cm >> 2) + m; // W row
        #pragma unroll
        for (int kt = 0; kt < 2; ++kt) {
            const float* wr = W_hh + arow * H_DIM + kt * 32 + q * 8;
            float wt[8];
            float4 wa = *(const float4*)wr;
            float4 wb = *(const float4*)(wr + 4);
            wt[0]=wa.x*LOG2E; wt[1]=wa.y*LOG2E; wt[2]=wa.z*LOG2E; wt[3]=wa.w*LOG2E;
            wt[4]=wb.x*LOG2E; wt[5]=wb.y*LOG2E; wt[6]=wb.z*LOG2E; wt[7]=wb.w*LOG2E;
            Whh[m][kt] = pack_frag(wt);
        }
        {
            const float* ir = W_ih + arow * I_DIM + q * 8;
            float wt[8];
            float4 ia = *(const float4*)ir;
            wt[0]=ia.x*LOG2E; wt[1]=ia.y*LOG2E; wt[2]=ia.z*LOG2E; wt[3]=ia.w*LOG2E;
            if (q < 3) {
                float4 ib = *(const float4*)(ir + 4);
                wt[4]=ib.x*LOG2E; wt[5]=ib.y*LOG2E; wt[6]=ib.z*LOG2E; wt[7]=ib.w*LOG2E;
            } else { wt[4]=0.f; wt[5]=0.f; wt[6]=0.f; wt[7]=0.f; }
            split_frag(wt, Wih_hi[m], Wih_lo[m]);
        }
        #pragma unroll
        for (int r = 0; r < 4; ++r) {
            const int row = r * H_DIM + wv * 8 + 2 * q + m;
            bias_c[m][r] = (b_ih[row] + b_hh[row]) * LOG2E;
        }
    }

    // zero h buffers (h0 = 0)
    for (int i = tid; i < 1024; i += NTHREADS)
        ((unsigned*)hbuf)[i] = 0u;

    // ---- x staging, balanced across ALL 8 waves: even lanes each handle one
    // float4 (item = (tts, dl, ps)); removes the waves-0-3 barrier skew.
    const int sitem = wv * 32 + (lane >> 1);      // 0..255
    const bool sact = (lane & 1) == 0;
    const int tts = sitem >> 7;                   // timestep within chunk
    const int dl  = (sitem >> 1) & 63;            // data-lane 0..63
    const int ps  = sitem & 1;                    // which half of the frag
    const int fo  = (dl >> 4) * 8 + ps * 4;       // float offset 0..28
    const bool sval = sact && (fo < I_DIM);       // fo==28 -> zero pad
    const float* xbase = x + (size_t)(b0 + (dl & 15)) * T_DIM * I_DIM + fo;

    auto load_x4 = [&](int t) -> float4 {
        if (!sval) return float4{0.f, 0.f, 0.f, 0.f};
        return *(const float4*)(xbase + (size_t)t * I_DIM);
    };
    auto pack_store_x = [&](int slot, const float4& v) {
        uint2 pw;
        pw.x = pack_pair(v.x, v.y);
        pw.y = pack_pair(v.z, v.w);
        *(uint2*)&xbuf[slot][tts][dl * 4 + 2 * ps] = pw;
    };

    // ---- prologue: xbuf[0]=x(ch0), xbuf[1]=x(ch1); xw(ch0) in regs;
    // X frags for xw(ch1) in regs; xs <- x(ch2)
    if (sact) {
        pack_store_x(0, load_x4(tts));
        pack_store_x(1, load_x4(2 + tts));
    }
    __syncthreads();

    f32x4 xwA[4], xwB[4];   // [tt*2+m], ping-ponged across chunks
    {
        bf16x8 Xa = __builtin_bit_cast(bf16x8, *(const u32x4*)&xbuf[0][0][lane * 4]);
        bf16x8 Xb = __builtin_bit_cast(bf16x8, *(const u32x4*)&xbuf[0][1][lane * 4]);
        #pragma unroll
        for (int m = 0; m < 2; ++m) {
            f32x4 a = MFMA(Wih_hi[m], Xa, bias_c[m]);
            a = MFMA(Wih_lo[m], Xa, a);
            xwA[m] = a;
            f32x4 b = MFMA(Wih_hi[m], Xb, bias_c[m]);
            b = MFMA(Wih_lo[m], Xb, b);
            xwA[2 + m] = b;
        }
    }
    // X frags for xw(ch1): pre-loaded into registers (NOT read post-barrier)
    bf16x8 X0c = __builtin_bit_cast(bf16x8, *(const u32x4*)&xbuf[1][0][lane * 4]);
    bf16x8 X1c = __builtin_bit_cast(bf16x8, *(const u32x4*)&xbuf[1][1][lane * 4]);

    float4 xs = load_x4(4 + tts);   // x(chunk 2); zero for inactive lanes
    __syncthreads();   // prologue xbuf[0] reads drained before ch0 overwrites

    float2 c_st = {0.f, 0.f};   // 2L*c for the lane's 2 cells
    // h write dword: row-pair rp = wv*4+q, batch cm
    const int hdw = 256 * (wv >> 2) + 64 * (wv & 3) + 4 * cm + q;

    const f32x4 zeroC = {0.f, 0.f, 0.f, 0.f};

    // One recurrence step. Split-K: 4 independent rec-MFMAs (chain entry =
    // H1 arrival + 1 MFMA + add, not 2 chained MFMAs). Optionally prefetches
    // next chunk's X frags right after the H reads — their latency hides
    // under the activation chain, keeping the post-barrier burst H-only.
    auto rec_step = [&](const unsigned* hrd, unsigned* hwr,
                        f32x4 xw0, f32x4 xw1, bf16x8 X,
                        f32x4& xn0, f32x4& xn1,
                        const unsigned* xnxt, bf16x8& NX0, bf16x8& NX1) {
        bf16x8 H0 = __builtin_bit_cast(bf16x8, *(const u32x4*)&hrd[lane * 4]);
        bf16x8 H1 = __builtin_bit_cast(bf16x8, *(const u32x4*)&hrd[256 + lane * 4]);
        f32x4 a0 = MFMA(Whh[0][0], H0, xw0);
        f32x4 a1 = MFMA(Whh[1][0], H0, xw1);
        f32x4 b0 = MFMA(Whh[0][1], H1, zeroC);
        f32x4 b1 = MFMA(Whh[1][1], H1, zeroC);
        if (xnxt) {   // wave-uniform; issued after the H reads
            NX0 = __builtin_bit_cast(bf16x8, *(const u32x4*)&xnxt[lane * 4]);
            NX1 = __builtin_bit_cast(bf16x8, *(const u32x4*)&xnxt[256 + lane * 4]);
        }
        // next-chunk xw MFMAs (off the serial chain; fill the matrix pipe)
        f32x4 n0 = MFMA(Wih_hi[0], X, bias_c[0]);
        f32x4 n1 = MFMA(Wih_hi[1], X, bias_c[1]);
        n0 = MFMA(Wih_lo[0], X, n0);
        n1 = MFMA(Wih_lo[1], X, n1);
        xn0 = n0; xn1 = n1;
        f32x4 s0 = a0 + b0;
        f32x4 s1 = a1 + b1;
        float h0 = cell_update(s0[0], s0[1], s0[2], s0[3], c_st.x);
        float h1 = cell_update(s1[0], s1[1], s1[2], s1[3], c_st.y);
        hwr[hdw] = pack_pair(h0, h1);   // rows (wv*8+2q, wv*8+2q+1), batch cm
    };

    auto chunk_body = [&](int ch, f32x4 (&xwC)[4], f32x4 (&xwN)[4]) {
        const int p = ch & 1;
        if (sact) pack_store_x(p, xs);   // x(ch+2); vmcnt wait lands here
        BAR();   // xbuf writes + prev h writes visible; post-bar burst = H only

        rec_step(hbuf[0], hbuf[1], xwC[0], xwC[1], X0c, xwN[0], xwN[1],
                 nullptr, X0c, X1c);

        // issue x(ch+3) load; stays in flight across barriers
        float4 xs2{0.f, 0.f, 0.f, 0.f};
        if (sact) {
            int tld = 2 * ch + 6 + tts;
            if (tld > T_DIM - 1) tld = T_DIM - 1;
            xs2 = load_x4(tld);
        }
        BAR();   // h(t0) visible
        // tt=1 also prefetches X(ch+2) from xbuf[p] (stable since bar1)
        rec_step(hbuf[1], hbuf[0], xwC[2], xwC[3], X1c, xwN[2], xwN[3],
                 &xbuf[p][0][0], X0c, X1c);
        xs = xs2;
    };

    for (int ch = 0; ch < T_DIM / 2; ch += 2) {
        chunk_body(ch,     xwA, xwB);   // ping-pong: no xw copy movs
        chunk_body(ch + 1, xwB, xwA);
    }

    __syncthreads();   // full drain; orders final hbuf[0] writes

    // ---- output head: final h(T) is in hbuf[0] (T even); layout unchanged
    if (tid < MB * OUT_DIM) {
        const int bb = tid / OUT_DIM;
        const int o  = tid % OUT_DIM;
        float s = b_out[o];
        const float* wo = W_out + o * H_DIM;
        #pragma unroll
        for (int u = 0; u < H_DIM; ++u) {
            const int dw = 256 * (u >> 5) + 64 * ((u >> 3) & 3) + 4 * bb + ((u >> 1) & 3);
            const int sh = (u & 1) * 16;
            float h = bfbits2f((hbuf[0][dw] >> sh) & 0xFFFFu);
            s += h * wo[u];
        }
        out[(size_t)(b0 + bb) * OUT_DIM + o] = s;
    }
}

extern "C" void kernel_launch(void* const* d_in, const int* in_sizes, int n_in,
                              void* d_out, int out_size, void* d_ws, size_t ws_size,
                              hipStream_t stream) {
    const float* x     = (const float*)d_in[0];
    const float* W_ih  = (const float*)d_in[1];
    const float* W_hh  = (const float*)d_in[2];
    const float* b_ih  = (const float*)d_in[3];
    const float* b_hh  = (const float*)d_in[4];
    const float* W_out = (const float*)d_in[5];
    const float* b_out = (const float*)d_in[6];
    float* out = (float*)d_out;

    dim3 grid(B_DIM / MB);    // 256 blocks -> 1 per CU
    dim3 block(NTHREADS);     // 8 symmetric waves = 2/SIMD
    lstm_mfma_kernel<<<grid, block, 0, stream>>>(
        x, W_ih, W_hh, b_ih, b_hh, W_out, b_out, out);
}